// Round 1
// baseline (190.040 us; speedup 1.0000x reference)
//
#include <hip/hip_runtime.h>

#define HH 479
#define WW 639
#define BATCH 8

// depth layout: (B,1,H,W) -> b*H*W + r*W + c
// output pixel (i,j), i in [0,479), j in [0,639): window r in [i-4,i+3], c in [j-4,j+3]
// a_c = (c - 319.5)/FX, b_r = (r - 239.5)/FY; point p = d*(a,b,1)

__device__ __forceinline__ void solve_normal(
    float xx, float xy, float xz, float yy, float yz, float zz,
    float xs, float ys, float zs,
    float a_c, float b_c, float d0,
    float* nx, float* ny, float* nz)
{
    // ATA + eps*I, solved in double (f32 Cramer has ~1e8 cancellation at corners)
    const double EPSV = 1e-6;
    double p = (double)xx + EPSV, q = (double)xy, r = (double)xz;
    double s = (double)yy + EPSV, t = (double)yz, u = (double)zz + EPSV;
    double c00 = s * u - t * t;
    double c01 = r * t - q * u;
    double c02 = q * t - r * s;
    double det = p * c00 + q * c01 + r * c02;
    double c11 = p * u - r * r;
    double c12 = q * r - p * t;
    double c22 = p * s - q * q;
    double m0 = c00 * (double)xs + c01 * (double)ys + c02 * (double)zs;
    double m1 = c01 * (double)xs + c11 * (double)ys + c12 * (double)zs;
    double m2 = c02 * (double)xs + c12 * (double)ys + c22 * (double)zs;
    // n = m/det; unit(n) = m * sign(det)/|m|
    double nrm = sqrt(m0 * m0 + m1 * m1 + m2 * m2);
    double inv = 1.0 / nrm;
    if (det < 0.0) inv = -inv;
    double ux = m0 * inv, uy = m1 * inv, uz = m2 * inv;
    // flip so n . xyz <= 0 ; xyz = d0*(a_c, b_c, 1)
    double dot = (double)d0 * (ux * (double)a_c + uy * (double)b_c + uz);
    if (dot > 0.0) { ux = -ux; uy = -uy; uz = -uz; }
    // mask: where(depth > 0, n, 0)
    if (!(d0 > 0.0f)) { ux = 0.0; uy = 0.0; uz = 0.0; }
    *nx = (float)ux; *ny = (float)uy; *nz = (float)uz;
}

__global__ __launch_bounds__(256)
void ppal_main(const float* __restrict__ pred, const float* __restrict__ gt,
               double* __restrict__ acc)
{
    const int tx = threadIdx.x;        // 0..15
    const int ty = threadIdx.y;        // 0..15
    const int tid = ty * 16 + tx;
    const int j0 = blockIdx.x * 16;
    const int i0 = blockIdx.y * 16;
    const int b  = blockIdx.z;

    // tile needs rows i0-4 .. i0+18 (23), cols j0-4 .. j0+18 (23); stride 24 -> 2 lanes/bank (free)
    __shared__ float sd[2][23 * 24];

    const float* src0 = pred + (size_t)b * (HH * WW);
    const float* src1 = gt   + (size_t)b * (HH * WW);
    for (int idx = tid; idx < 23 * 23; idx += 256) {
        int lr = idx / 23, lc = idx - lr * 23;
        int r = i0 - 4 + lr, c = j0 - 4 + lc;
        bool ok = (r >= 0) && (r < HH) && (c >= 0) && (c < WW);
        int off = r * WW + c;
        sd[0][lr * 24 + lc] = ok ? src0[off] : 0.0f;
        sd[1][lr * 24 + lc] = ok ? src1[off] : 0.0f;
    }
    __syncthreads();

    const int i = i0 + ty, j = j0 + tx;
    const bool valid = (i < HH) && (j < WW);

    float contrib = 0.0f;
    if (valid) {
        float aa[8], bb[8];
#pragma unroll
        for (int t = 0; t < 8; ++t) {
            aa[t] = ((float)(j - 4 + t) - 319.5f) * (1.0f / 518.857f);
            bb[t] = ((float)(i - 4 + t) - 239.5f) * (1.0f / 519.469f);
        }

        float n2[2][3];
#pragma unroll 1
        for (int k = 0; k < 2; ++k) {
            float xx = 0.f, xy = 0.f, xz = 0.f, yy = 0.f, yz = 0.f, zz = 0.f;
            float xs = 0.f, ys = 0.f, zs = 0.f;
#pragma unroll
            for (int dr = 0; dr < 8; ++dr) {
                float bv = bb[dr];
#pragma unroll
                for (int dc = 0; dc < 8; ++dc) {
                    float d  = sd[k][(ty + dr) * 24 + (tx + dc)];
                    float ad = aa[dc] * d;
                    float bd = bv * d;
                    xx += ad * ad; xy += ad * bd; xz += ad * d;
                    yy += bd * bd; yz += bd * d;  zz += d * d;
                    xs += ad;      ys += bd;      zs += d;
                }
            }
            float d0 = sd[k][(ty + 4) * 24 + (tx + 4)];
            solve_normal(xx, xy, xz, yy, yz, zz, xs, ys, zs,
                         aa[4], bb[4], d0, &n2[k][0], &n2[k][1], &n2[k][2]);
        }
        contrib = fabsf(n2[0][0] - n2[1][0])
                + fabsf(n2[0][1] - n2[1][1])
                + fabsf(n2[0][2] - n2[1][2]);
    }

    // wave reduce (64 lanes) then cross-wave via LDS, one f64 atomic per block
    float v = contrib;
#pragma unroll
    for (int off = 32; off > 0; off >>= 1) v += __shfl_down(v, off, 64);
    __shared__ float wsum[4];
    int wid = tid >> 6, lane = tid & 63;
    if (lane == 0) wsum[wid] = v;
    __syncthreads();
    if (tid == 0) {
        double bs = (double)wsum[0] + (double)wsum[1] + (double)wsum[2] + (double)wsum[3];
        atomicAdd(acc, bs);
    }
}

__global__ void ppal_finalize(const double* __restrict__ acc, float* __restrict__ out)
{
    // mean over B*3*H*W = 8*3*479*639 = 7,345,944
    out[0] = (float)(acc[0] * (1.0 / 7345944.0));
}

extern "C" void kernel_launch(void* const* d_in, const int* in_sizes, int n_in,
                              void* d_out, int out_size, void* d_ws, size_t ws_size,
                              hipStream_t stream)
{
    const float* pred = (const float*)d_in[0];
    const float* gt   = (const float*)d_in[1];
    float* out  = (float*)d_out;
    double* acc = (double*)d_ws;

    hipMemsetAsync(acc, 0, sizeof(double), stream);

    dim3 grid((WW + 15) / 16, (HH + 15) / 16, BATCH);  // 40 x 30 x 8 = 9600 blocks
    dim3 block(16, 16);
    ppal_main<<<grid, block, 0, stream>>>(pred, gt, acc);
    ppal_finalize<<<1, 1, 0, stream>>>(acc, out);
}